// Round 5
// baseline (3517.718 us; speedup 1.0000x reference)
//
#include <hip/hip_runtime.h>
#include <stdint.h>

// Problem constants (from reference)
#define N_VOX    200000
#define C_CH     64
#define K_OFF    27
#define M_PAIRS  100000
#define KM       (K_OFF * M_PAIRS)              // 2,700,000 pairs
#define TILE     64                             // output voxels per conv block (o>>6)
#define NT       (N_VOX / TILE)                 // 3125 tiles (exact: 3125*64=200000)
#define NB       (NT * K_OFF)                   // 84,375 (out-tile,k) buckets
#define OLDS_STRIDE 68                          // padded LDS row stride (floats)
#define WBN      (K_OFF * 4096)                 // 110592 weight elems per layer
#define EPS_BN   1e-5f
#define NW       8                              // waves per conv block
#define TCCAP    128                            // chunk-descriptor capacity per tile
#define DUMMY    TILE                           // dummy LDS row for pad slots

typedef __attribute__((ext_vector_type(8))) short   short8_t;  // 8 x bf16
typedef __attribute__((ext_vector_type(4))) float   f32x4;
typedef __attribute__((ext_vector_type(4))) unsigned short u16x4;

__device__ __forceinline__ unsigned short f2bf(float f) {
    union { float f; unsigned u; } v; v.f = f;
    unsigned r = v.u + 0x7FFFu + ((v.u >> 16) & 1u);   // RTNE
    return (unsigned short)(r >> 16);
}

// ---------- prep: w1/w2 -> bf16 B-frag layout, BN fold, out-bucket histogram ----------
__global__ void prep_kernel(const float* __restrict__ w1, const float* __restrict__ w2,
                            const float* __restrict__ g1, const float* __restrict__ b1,
                            const float* __restrict__ m1, const float* __restrict__ v1,
                            const float* __restrict__ g2, const float* __restrict__ b2,
                            const float* __restrict__ m2, const float* __restrict__ v2,
                            const int* __restrict__ out_map,
                            unsigned short* __restrict__ wb1, unsigned short* __restrict__ wb2,
                            float* __restrict__ sb1, float* __restrict__ sb2,
                            int* __restrict__ cnt)
{
    long j = (long)blockIdx.x * blockDim.x + threadIdx.x;
    if (j < 2 * WBN) {
        const float* w = (j < WBN) ? w1 : w2;
        unsigned short* wb = (j < WBN) ? wb1 : wb2;
        int o = (int)(j >= WBN ? j - WBN : j);
        int k   = o >> 12;
        int rem = o & 4095;
        int t  = rem >> 11;
        int sl = (rem >> 9) & 3;
        int d  = (rem >> 3) & 63;
        int jj = rem & 7;
        int c  = t * 32 + sl * 8 + jj;
        wb[o] = f2bf(w[k * 4096 + c * 64 + d]);
        return;
    }
    j -= 2 * WBN;
    if (j < 64) {
        float s = g1[j] * rsqrtf(v1[j] + EPS_BN);
        sb1[j] = s; sb1[64 + j] = b1[j] - m1[j] * s;
        return;
    }
    if (j < 128) {
        int c = (int)j - 64;
        float s = g2[c] * rsqrtf(v2[c] + EPS_BN);
        sb2[c] = s; sb2[64 + c] = b2[c] - m2[c] * s;
        return;
    }
    j -= 128;
    if (j < KM) {
        int p = (int)j;
        int k = p / M_PAIRS;
        int o = out_map[p];
        atomicAdd(&cnt[(o >> 6) * K_OFF + k], 1);
    }
}

// ---------------- exclusive scan ----------------
__global__ void scan_kernel(const int* __restrict__ cnt, int* __restrict__ offs, int n) {
    __shared__ int part[1024];
    int t = threadIdx.x;
    int SEG = (n + 1023) / 1024;
    int beg = t * SEG;
    int s = 0;
    for (int i = 0; i < SEG; ++i) { int idx = beg + i; if (idx < n) s += cnt[idx]; }
    part[t] = s;
    __syncthreads();
    for (int d = 1; d < 1024; d <<= 1) {
        int v = (t >= d) ? part[t - d] : 0;
        __syncthreads();
        part[t] += v;
        __syncthreads();
    }
    int run = (t > 0) ? part[t - 1] : 0;
    for (int i = 0; i < SEG; ++i) {
        int idx = beg + i;
        if (idx <= n) offs[idx] = run;
        if (idx < n) run += cnt[idx];
    }
}

// ---------- out-sorted payload: iidx (18 bits) | out_local (bits 18..23) ----------
__global__ void scatter_kernel(const int* __restrict__ in_map, const int* __restrict__ out_map,
                               const int* __restrict__ offs, int* __restrict__ cursor,
                               unsigned int* __restrict__ payload)
{
    int p = blockIdx.x * 256 + threadIdx.x;
    if (p >= KM) return;
    int k = p / M_PAIRS;
    int o = out_map[p];
    int key = (o >> 6) * K_OFF + k;
    int pos = offs[key] + atomicAdd(&cursor[key], 1);
    payload[pos] = (unsigned)in_map[p] | ((unsigned)(o & (TILE - 1)) << 18);
}

// ---------- Phase A: streaming gather for one group ----------
// 4 threads per pair; sequential payload read, random row read, coalesced gbuf write.
template<int IS_F32>
__global__ __launch_bounds__(256) void gather_kernel(const void* __restrict__ srcv,
                                                     const unsigned int* __restrict__ payload,
                                                     const int* __restrict__ p0p,
                                                     const int* __restrict__ p1p,
                                                     unsigned short* __restrict__ gbuf)
{
    int rel = blockIdx.x * 64 + (threadIdx.x >> 2);
    int j   = threadIdx.x & 3;
    int P0 = p0p[0];
    if (P0 + rel >= p1p[0]) return;
    unsigned pl = payload[P0 + rel];
    int iidx = (int)(pl & 0x3FFFFu);
    uint4* dst = (uint4*)(gbuf + (size_t)rel * 64) + 2 * j;
    if (IS_F32) {
        const f32x4* sp = (const f32x4*)((const float*)srcv + (size_t)iidx * 64) + 4 * j;
        f32x4 v0 = sp[0], v1 = sp[1], v2 = sp[2], v3 = sp[3];
        union { unsigned short us[16]; uint4 q[2]; } u;
        #pragma unroll
        for (int ii = 0; ii < 4; ++ii) {
            u.us[ii]      = f2bf(v0[ii]);
            u.us[4 + ii]  = f2bf(v1[ii]);
            u.us[8 + ii]  = f2bf(v2[ii]);
            u.us[12 + ii] = f2bf(v3[ii]);
        }
        dst[0] = u.q[0];
        dst[1] = u.q[1];
    } else {
        const uint4* sp = (const uint4*)((const unsigned short*)srcv + (size_t)iidx * 64) + 2 * j;
        uint4 a = sp[0], b = sp[1];
        dst[0] = a;
        dst[1] = b;
    }
}

// ---------------- Phase B: streaming conv (+BN [+ReLU] [+residual]) ----------------
// Block = 64-voxel output tile; A-operand streams gbuf sequentially (out-sorted).
template<int LAYER>
__global__ __launch_bounds__(512, 6) void conv_kernel(
    const unsigned short* __restrict__ gbuf,    // gathered bf16 rows for this group
    const unsigned short* __restrict__ wb,      // pre-swizzled bf16 weights
    const unsigned int* __restrict__ payload,   // for oloc
    const int* __restrict__ offs,
    const float* __restrict__ sb,               // [0:64) scale, [64:128) shift
    const float* __restrict__ xres,             // LAYER==1: residual (f32)
    void* __restrict__ outp,                    // LAYER==0: bf16 h; LAYER==1: f32 d_out
    int tg0)                                    // first tile of this group
{
    __shared__ float olds[(TILE + 1) * OLDS_STRIDE];   // 17.7 KB (+1 dummy row)
    __shared__ int soffs[K_OFF + 1];
    __shared__ int scum[K_OFF + 1];
    __shared__ int desc[TCCAP];                        // k | relbase<<5 | relend<<18

    const int tile = tg0 + blockIdx.x;
    const int tid = threadIdx.x;
    const int pg = offs[tg0 * K_OFF];

    if (tid <= K_OFF) soffs[tid] = offs[tile * K_OFF + tid];
    {
        f32x4* o4 = (f32x4*)olds;
        const int n4 = (TILE + 1) * OLDS_STRIDE / 4;   // 1105
        f32x4 z = {0.f, 0.f, 0.f, 0.f};
        for (int i = tid; i < n4; i += 512) o4[i] = z;
    }
    __syncthreads();

    const int p0 = soffs[0];
    if (tid < 32) {
        int c = (tid < K_OFF) ? ((soffs[tid + 1] - soffs[tid] + 15) >> 4) : 0;
        int v = c;
        #pragma unroll
        for (int d = 1; d < 32; d <<= 1) {
            int u = __shfl_up(v, d, 32);
            if (tid >= d) v += u;
        }
        if (tid == 0) scum[0] = 0;
        if (tid < K_OFF) scum[tid + 1] = v;
    }
    __syncthreads();
    if (tid < K_OFF) {
        int c0 = scum[tid], c1 = scum[tid + 1];
        int base = soffs[tid] - p0;
        int end  = soffs[tid + 1] - p0;
        for (int c = c0; c < c1; ++c)
            if (c < TCCAP) desc[c] = tid | ((base + (c - c0) * 16) << 5) | (end << 18);
    }
    __syncthreads();

    const int TC = scum[K_OFF];
    const int lane  = tid & 63;
    const int wid   = tid >> 6;
    const int r     = lane & 15;
    const int sfour = lane >> 4;
    const int gofs  = p0 - pg;                  // group-relative base of this tile's rows

    const int CPW = (TC + NW - 1) >> 3;
    int w0 = wid * CPW; if (w0 > TC) w0 = TC;
    int w1 = w0 + CPW;  if (w1 > TC) w1 = TC;

    short8_t B0[4], B1[4];
    int kcur = -1;

    #pragma unroll 1
    for (int t = w0; t < w1; ++t) {
        int d;
        if (t < TCCAP) d = desc[t];
        else {
            int k = 0;
            while (k < K_OFF - 1 && scum[k + 1] <= t) ++k;
            d = k | (((soffs[k] - p0) + (t - scum[k]) * 16) << 5)
                  | ((soffs[k + 1] - p0) << 18);
        }
        int kk = __builtin_amdgcn_readfirstlane(d & 31);
        if (kk != kcur) {
            kcur = kk;
            const short8_t* wbk = (const short8_t*)(wb + kcur * 4096);
            #pragma unroll
            for (int n = 0; n < 4; ++n) {
                B0[n] = wbk[sfour * 64 + n * 16 + r];
                B1[n] = wbk[(4 + sfour) * 64 + n * 16 + r];
            }
        }
        int rb = (d >> 5) & 0x1FFF;
        int re = d >> 18;
        int ii = rb + r;
        unsigned pl = payload[p0 + ii];                       // sequential
        const short8_t* xr = (const short8_t*)(gbuf + (size_t)(gofs + ii) * 64);  // sequential
        short8_t A0 = xr[sfour];
        short8_t A1 = xr[4 + sfour];
        int ol = (ii < re) ? (int)((pl >> 18) & 63) : DUMMY;

        f32x4 acc[4] = {{0,0,0,0},{0,0,0,0},{0,0,0,0},{0,0,0,0}};
        #pragma unroll
        for (int n = 0; n < 4; ++n) {
            acc[n] = __builtin_amdgcn_mfma_f32_16x16x32_bf16(A0, B0[n], acc[n], 0, 0, 0);
            acc[n] = __builtin_amdgcn_mfma_f32_16x16x32_bf16(A1, B1[n], acc[n], 0, 0, 0);
        }

        // D layout: col = n*16 + r (channel), row = sfour*4 + j (pair slot)
        #pragma unroll
        for (int j = 0; j < 4; ++j) {
            int dr = sfour * 4 + j;
            int olr = __shfl(ol, dr, 64);
            float* rp = &olds[olr * OLDS_STRIDE];
            #pragma unroll
            for (int n = 0; n < 4; ++n)
                atomicAdd(&rp[n * 16 + r], acc[n][j]);
        }
    }
    __syncthreads();

    // epilogue: BN fold (+relu / +residual+relu)
    const int row0 = tile * TILE;
    const f32x4* sc4 = (const f32x4*)sb;
    const f32x4* bi4 = (const f32x4*)(sb + 64);
    for (int e4 = tid; e4 < TILE * 16; e4 += 512) {
        int row = e4 >> 4, q = e4 & 15;
        f32x4 v = *(const f32x4*)&olds[row * OLDS_STRIDE + q * 4];
        v = v * sc4[q] + bi4[q];
        int g4 = (row0 + row) * 16 + q;
        if (LAYER == 0) {
            u16x4 h;
            #pragma unroll
            for (int ii = 0; ii < 4; ++ii) {
                float f = v[ii] > 0.f ? v[ii] : 0.f;
                h[ii] = f2bf(f);
            }
            ((u16x4*)outp)[g4] = h;
        } else {
            f32x4 xr = ((const f32x4*)xres)[g4];
            v = v + xr;
            #pragma unroll
            for (int ii = 0; ii < 4; ++ii) v[ii] = v[ii] > 0.f ? v[ii] : 0.f;
            ((f32x4*)outp)[g4] = v;
        }
    }
}

// ---------------- launch ----------------
extern "C" void kernel_launch(void* const* d_in, const int* in_sizes, int n_in,
                              void* d_out, int out_size, void* d_ws, size_t ws_size,
                              hipStream_t stream)
{
    const float* x  = (const float*)d_in[0];
    const float* w1 = (const float*)d_in[1];
    const float* w2 = (const float*)d_in[2];
    const float* g1 = (const float*)d_in[3];
    const float* b1 = (const float*)d_in[4];
    const float* m1 = (const float*)d_in[5];
    const float* v1 = (const float*)d_in[6];
    const float* g2 = (const float*)d_in[7];
    const float* b2 = (const float*)d_in[8];
    const float* m2 = (const float*)d_in[9];
    const float* v2 = (const float*)d_in[10];
    const int* in_map  = (const int*)d_in[11];
    const int* out_map = (const int*)d_in[12];

    // pick group count by workspace budget (gbuf = one group of gathered rows)
    const int    ngs[4]  = {4, 8, 16, 32};
    const int    caps[4] = {690000, 345000, 175000, 90000};  // >=20 sigma over mean group pairs
    const size_t fixedB  = 40u * 1024 * 1024;                // cnt/cursor/offs/sb/wb/payload/hb (~37.9 MB)
    int NG = 32, CAP = 90000;
    for (int i = 0; i < 4; ++i) {
        size_t need = fixedB + ((size_t)caps[i] + 32) * 128;
        if (ws_size >= need) { NG = ngs[i]; CAP = caps[i]; break; }
    }
    const int TPG = (NT + NG - 1) / NG;

    char* ws = (char*)d_ws;
    size_t off = 0;
    auto alloc = [&](size_t bytes) -> void* {
        void* p = ws + off;
        off = (off + bytes + 255) & ~(size_t)255;
        return p;
    };
    int*            cnt     = (int*)alloc((size_t)NB * 4);
    int*            cursor  = (int*)alloc((size_t)NB * 4);
    size_t zlen = (size_t)((char*)cursor - (char*)cnt) + (size_t)NB * 4;
    int*            offs    = (int*)alloc((size_t)(NB + 1) * 4);
    float*          sb1     = (float*)alloc(128 * 4);
    float*          sb2     = (float*)alloc(128 * 4);
    unsigned short* wb1     = (unsigned short*)alloc((size_t)WBN * 2);
    unsigned short* wb2     = (unsigned short*)alloc((size_t)WBN * 2);
    unsigned int*   payload = (unsigned int*)alloc((size_t)KM * 4);
    unsigned short* hb      = (unsigned short*)alloc((size_t)N_VOX * C_CH * 2);
    unsigned short* gbuf    = (unsigned short*)alloc(((size_t)CAP + 32) * 128);

    hipMemsetAsync(cnt, 0, zlen, stream);

    const long TOT = 2 * WBN + 128 + KM;
    int prep_blocks = (int)((TOT + 255) / 256);
    prep_kernel<<<prep_blocks, 256, 0, stream>>>(w1, w2, g1, b1, m1, v1,
                                                 g2, b2, m2, v2, out_map,
                                                 wb1, wb2, sb1, sb2, cnt);

    scan_kernel<<<1, 1024, 0, stream>>>(cnt, offs, NB);

    int pair_blocks = (KM + 255) / 256;
    scatter_kernel<<<pair_blocks, 256, 0, stream>>>(in_map, out_map, offs, cursor, payload);

    int gat_blocks = (CAP + 63) / 64;
    for (int g = 0; g < NG; ++g) {
        int tg0 = g * TPG;
        int tg1 = (g + 1) * TPG; if (tg1 > NT) tg1 = NT;
        if (tg0 >= tg1) break;
        gather_kernel<1><<<gat_blocks, 256, 0, stream>>>(x, payload,
                                                         offs + (size_t)tg0 * K_OFF,
                                                         offs + (size_t)tg1 * K_OFF, gbuf);
        conv_kernel<0><<<tg1 - tg0, 512, 0, stream>>>(gbuf, wb1, payload, offs, sb1,
                                                      nullptr, hb, tg0);
    }
    for (int g = 0; g < NG; ++g) {
        int tg0 = g * TPG;
        int tg1 = (g + 1) * TPG; if (tg1 > NT) tg1 = NT;
        if (tg0 >= tg1) break;
        gather_kernel<0><<<gat_blocks, 256, 0, stream>>>(hb, payload,
                                                         offs + (size_t)tg0 * K_OFF,
                                                         offs + (size_t)tg1 * K_OFF, gbuf);
        conv_kernel<1><<<tg1 - tg0, 512, 0, stream>>>(gbuf, wb2, payload, offs, sb2,
                                                      x, d_out, tg0);
    }
}

// Round 6
// 1693.173 us; speedup vs baseline: 2.0776x; 2.0776x over previous
//
#include <hip/hip_runtime.h>
#include <stdint.h>

// Problem constants
#define N_VOX    200000
#define C_CH     64
#define K_OFF    27
#define M_PAIRS  100000
#define KM       (K_OFF * M_PAIRS)          // 2,700,000 pairs
#define TILE     64                         // output voxels per tile (o>>6)
#define NT       (N_VOX / TILE)             // 3125 tiles exactly
#define NB       (NT * K_OFF)               // 84375 (tile,k) buckets
#define WBN      (K_OFF * 4096)             // 110592 weight elems per layer
#define EPS_BN   1e-5f
#define CDCAP    (KM / 16 + NB + 64)        // max total chunks

typedef __attribute__((ext_vector_type(8))) short   short8_t;  // 8 x bf16
typedef __attribute__((ext_vector_type(4))) float   f32x4;

__device__ __forceinline__ unsigned short f2bf(float f) {
    union { float f; unsigned u; } v; v.f = f;
    unsigned r = v.u + 0x7FFFu + ((v.u >> 16) & 1u);   // RTNE
    return (unsigned short)(r >> 16);
}
__device__ __forceinline__ float bf2f(unsigned u16) {
    union { unsigned u; float f; } v; v.u = u16 << 16;
    return v.f;
}
// hb/Y flat bf16 index cs -> standard channel (position layout)
__device__ __forceinline__ int pmap(int cs) {
    int p = cs >> 1, h = cs & 1;
    return (p & 3) * 16 + (p >> 2) * 2 + h;
}

// ---------- prep: xb convert, w1 (std) / w2 (PMAP-Cin) B-frag swizzle, BN fold (position order), dual hist ----------
__global__ void prep_kernel(const float* __restrict__ x,
                            const float* __restrict__ w1, const float* __restrict__ w2,
                            const float* __restrict__ g1, const float* __restrict__ b1,
                            const float* __restrict__ m1, const float* __restrict__ v1,
                            const float* __restrict__ g2, const float* __restrict__ b2,
                            const float* __restrict__ m2, const float* __restrict__ v2,
                            const int* __restrict__ in_map, const int* __restrict__ out_map,
                            unsigned short* __restrict__ xb,
                            unsigned short* __restrict__ wb1, unsigned short* __restrict__ wb2,
                            float* __restrict__ sbp1, float* __restrict__ sbp2,
                            int* __restrict__ cnt, int* __restrict__ cnt3)
{
    long i = (long)blockIdx.x * blockDim.x + threadIdx.x;
    const long XBN = (long)N_VOX * C_CH;
    if (i < XBN) { xb[i] = f2bf(x[i]); return; }
    long j = i - XBN;
    if (j < 2 * WBN) {
        int isw2 = j >= WBN;
        int o = (int)(isw2 ? j - WBN : j);
        int k   = o >> 12;
        int rem = o & 4095;
        int t  = rem >> 11;
        int sl = (rem >> 9) & 3;
        int d  = (rem >> 3) & 63;
        int jj = rem & 7;
        int cs = t * 32 + sl * 8 + jj;      // A k-slot (flat bf16 index of input row)
        if (!isw2) wb1[o] = f2bf(w1[k * 4096 + cs * 64 + d]);
        else       wb2[o] = f2bf(w2[k * 4096 + pmap(cs) * 64 + d]);  // hb is position-permuted
        return;
    }
    j -= 2 * WBN;
    if (j < 128) {
        int L = (int)(j >= 64);
        int ch = (int)(j & 63);
        float gv = L ? g2[ch] : g1[ch];
        float vv = L ? v2[ch] : v1[ch];
        float mv = L ? m2[ch] : m1[ch];
        float bv = L ? b2[ch] : b1[ch];
        float s = gv * rsqrtf(vv + EPS_BN);
        float sh = bv - mv * s;
        int n = ch >> 4, rem = ch & 15, m = rem >> 1, h = rem & 1;
        int idx = 2 * (m * 4 + n) + h;      // position-mapped slot
        float* sbp = L ? sbp2 : sbp1;
        sbp[idx] = s; sbp[64 + idx] = sh;
        return;
    }
    j -= 128;
    if (j < KM) {
        int p = (int)j;
        int k = p / M_PAIRS;
        int o = out_map[p];
        atomicAdd(&cnt[(o >> 6) * K_OFF + k], 1);
        atomicAdd(&cnt3[o], 1);
    }
}

// ---------------- exclusive scan (mode 0: raw; mode 1: ceil(x/16)) ----------------
__global__ void scan_kernel(const int* __restrict__ cnt, int* __restrict__ offs,
                            int n, int mode) {
    __shared__ int part[1024];
    int t = threadIdx.x;
    int SEG = (n + 1023) / 1024;
    int beg = t * SEG;
    int s = 0;
    for (int i = 0; i < SEG; ++i) {
        int idx = beg + i;
        if (idx < n) { int c = cnt[idx]; s += mode ? ((c + 15) >> 4) : c; }
    }
    part[t] = s;
    __syncthreads();
    for (int d = 1; d < 1024; d <<= 1) {
        int v = (t >= d) ? part[t - d] : 0;
        __syncthreads();
        part[t] += v;
        __syncthreads();
    }
    int run = (t > 0) ? part[t - 1] : 0;
    for (int i = 0; i < SEG; ++i) {
        int idx = beg + i;
        if (idx <= n) offs[idx] = run;
        if (idx < n) { int c = cnt[idx]; run += mode ? ((c + 15) >> 4) : c; }
    }
}

// ---------- scatter both orders: payload[pos]=iidx ((tile,k)-sorted), perm[pos]=pos3 (o-sorted rank) ----------
__global__ void scatter_kernel(const int* __restrict__ in_map, const int* __restrict__ out_map,
                               const int* __restrict__ offs, int* __restrict__ cursor,
                               const int* __restrict__ ss3, int* __restrict__ cur3,
                               unsigned int* __restrict__ payload, unsigned int* __restrict__ perm)
{
    int p = blockIdx.x * 256 + threadIdx.x;
    if (p >= KM) return;
    int k = p / M_PAIRS;
    int o = out_map[p];
    int key = (o >> 6) * K_OFF + k;
    int pos = offs[key] + atomicAdd(&cursor[key], 1);
    payload[pos] = (unsigned)in_map[p];
    int pos3 = ss3[o] + atomicAdd(&cur3[o], 1);
    perm[pos] = (unsigned)pos3;
}

// ---------- build global chunk descriptors: k | pbase<<5 | pend<<27 ----------
__global__ void cdescb_kernel(const int* __restrict__ cnt, const int* __restrict__ offs,
                              const int* __restrict__ cdoffs, unsigned long long* __restrict__ cdesc)
{
    int b = blockIdx.x * 256 + threadIdx.x;
    if (b >= NB) return;
    int k = b % K_OFF;
    int c0 = cdoffs[b];
    int nchunk = cdoffs[b + 1] - c0;
    int base = offs[b];
    int end  = offs[b + 1];
    for (int i = 0; i < nchunk; ++i)
        cdesc[c0 + i] = (unsigned long long)k
                      | ((unsigned long long)(base + 16 * i) << 5)
                      | ((unsigned long long)end << 27);
}

// ---------- computeY: one chunk per wave; gather 16 rows, 8 MFMA, repack, random row write ----------
__global__ __launch_bounds__(256) void computeY_kernel(
    const unsigned short* __restrict__ xin,     // bf16 rows [N][64] (xb std / hb position-layout)
    const unsigned short* __restrict__ wb,      // pre-swizzled bf16 weights
    const unsigned int* __restrict__ payload,
    const unsigned int* __restrict__ perm,
    const unsigned long long* __restrict__ cdesc,
    const int* __restrict__ csp,                // &cdoffs[tg0*27]
    const int* __restrict__ cep,                // &cdoffs[tg1*27]
    const int* __restrict__ ygbp,               // &ss3[tg0*64]
    unsigned int* __restrict__ Y,               // rows of 32 u32 (bf16 pairs, position layout)
    int ycap)                                   // real rows capacity; dummies at ycap+8+
{
    int c = csp[0] + blockIdx.x * 4 + (threadIdx.x >> 6);
    if (c >= cep[0]) return;
    unsigned long long d = cdesc[c];
    int k     = (int)(d & 31);
    int pbase = (int)((d >> 5) & 0x3FFFFF);
    int pend  = (int)(d >> 27);
    int ygb = ygbp[0];
    int lane  = threadIdx.x & 63;
    int r     = lane & 15;
    int sfour = lane >> 4;
    int par   = lane & 1;

    int ii = pbase + r;
    bool real = ii < pend;
    int pidx = real ? ii : pbase;
    unsigned iidx = payload[pidx];
    int yr;
    if (real) {
        yr = (int)perm[pidx] - ygb;
        if (yr > ycap) yr = ycap;               // 13-sigma overflow guard
    } else {
        yr = ycap + 8 + (c & 63);               // spread dummy rows
    }

    const short8_t* xrow = (const short8_t*)(xin + (size_t)iidx * 64);
    short8_t A0 = xrow[sfour];
    short8_t A1 = xrow[4 + sfour];
    const short8_t* wbk = (const short8_t*)(wb + k * 4096);

    f32x4 acc[4] = {{0,0,0,0},{0,0,0,0},{0,0,0,0},{0,0,0,0}};
    #pragma unroll
    for (int n = 0; n < 4; ++n) {
        acc[n] = __builtin_amdgcn_mfma_f32_16x16x32_bf16(A0, wbk[sfour * 64 + n * 16 + r], acc[n], 0, 0, 0);
        acc[n] = __builtin_amdgcn_mfma_f32_16x16x32_bf16(A1, wbk[(4 + sfour) * 64 + n * 16 + r], acc[n], 0, 0, 0);
    }

    // repack D (col=n*16+r, row=sfour*4+j) into bf16 Y rows; lane-pair exchange packs ch pairs
    #pragma unroll
    for (int jj = 0; jj < 4; jj += 2) {
        uint4 w;
        unsigned* wp = (unsigned*)&w;
        #pragma unroll
        for (int n = 0; n < 4; ++n) {
            float mine = par ? acc[n][jj + 1] : acc[n][jj];
            float send = par ? acc[n][jj]     : acc[n][jj + 1];
            float t = __shfl_xor(send, 1, 64);
            float lo = par ? t : mine;
            float hi = par ? mine : t;
            wp[n] = (unsigned)f2bf(lo) | ((unsigned)f2bf(hi) << 16);
        }
        int Rw = sfour * 4 + jj + par;          // pair slot whose row this lane packs
        int yrow = __shfl(yr, Rw, 64);
        ((uint4*)Y)[(size_t)yrow * 8 + (r >> 1)] = w;
    }
}

// ---------- reduce: segmented sum of consecutive Y rows per output + BN(+relu)(+residual) ----------
template<int LAYER>
__global__ __launch_bounds__(256) void reduce_kernel(
    const unsigned int* __restrict__ Y,
    const int* __restrict__ ss3,
    const int* __restrict__ ygbp,
    const float* __restrict__ sbp,              // [0:64) scale, [64:128) shift (position order)
    const float* __restrict__ xres,             // LAYER==1 residual (std layout)
    void* __restrict__ outp,                    // L0: hb (bf16 position layout); L1: f32 std
    int obase, int oend)
{
    int w = blockIdx.x * 4 + (threadIdx.x >> 6);
    int lane = threadIdx.x & 63;
    int q = lane & 7;
    int og = obase + w * 8 + (lane >> 3);
    if (og >= oend) return;
    int ygb = ygbp[0];
    int s0 = ss3[og], s1 = ss3[og + 1];
    int i0 = s0 - ygb, cnt = s1 - s0;

    float sum[8] = {0.f,0.f,0.f,0.f,0.f,0.f,0.f,0.f};
    for (int i = 0; i < cnt; ++i) {
        uint4 v = ((const uint4*)Y)[(size_t)(i0 + i) * 8 + q];
        const unsigned* vp = (const unsigned*)&v;
        #pragma unroll
        for (int t = 0; t < 4; ++t) {
            sum[2 * t]     += bf2f(vp[t] & 0xFFFFu);
            sum[2 * t + 1] += bf2f(vp[t] >> 16);
        }
    }

    const float2* sc2 = (const float2*)sbp;
    const float2* sh2 = (const float2*)(sbp + 64);
    if (LAYER == 0) {
        uint4 o4;
        unsigned* op = (unsigned*)&o4;
        #pragma unroll
        for (int t = 0; t < 4; ++t) {
            int p = q * 4 + t;
            float a = sum[2 * t]     * sc2[p].x + sh2[p].x;
            float b = sum[2 * t + 1] * sc2[p].y + sh2[p].y;
            a = a > 0.f ? a : 0.f;
            b = b > 0.f ? b : 0.f;
            op[t] = (unsigned)f2bf(a) | ((unsigned)f2bf(b) << 16);
        }
        ((uint4*)outp)[(size_t)og * 8 + q] = o4;            // hb row, position layout
    } else {
        float* out = (float*)outp;
        #pragma unroll
        for (int t = 0; t < 4; ++t) {
            int p = q * 4 + t;
            int ch0 = t * 16 + 2 * q;                        // std channel of (p, h=0)
            float2 xr = *(const float2*)(xres + (size_t)og * 64 + ch0);
            float a = sum[2 * t]     * sc2[p].x + sh2[p].x + xr.x;
            float b = sum[2 * t + 1] * sc2[p].y + sh2[p].y + xr.y;
            a = a > 0.f ? a : 0.f;
            b = b > 0.f ? b : 0.f;
            *(float2*)(out + (size_t)og * 64 + ch0) = make_float2(a, b);
        }
    }
}

// ---------------- launch ----------------
extern "C" void kernel_launch(void* const* d_in, const int* in_sizes, int n_in,
                              void* d_out, int out_size, void* d_ws, size_t ws_size,
                              hipStream_t stream)
{
    const float* x  = (const float*)d_in[0];
    const float* w1 = (const float*)d_in[1];
    const float* w2 = (const float*)d_in[2];
    const float* g1 = (const float*)d_in[3];
    const float* b1 = (const float*)d_in[4];
    const float* m1 = (const float*)d_in[5];
    const float* v1 = (const float*)d_in[6];
    const float* g2 = (const float*)d_in[7];
    const float* b2 = (const float*)d_in[8];
    const float* m2 = (const float*)d_in[9];
    const float* v2 = (const float*)d_in[10];
    const int* in_map  = (const int*)d_in[11];
    const int* out_map = (const int*)d_in[12];

    char* ws = (char*)d_ws;
    size_t off = 0;
    auto alloc = [&](size_t bytes) -> void* {
        void* p = ws + off;
        off = (off + bytes + 255) & ~(size_t)255;
        return p;
    };
    // zeroed region: cnt, cursor, cnt3, cur3 (contiguous)
    int* cnt    = (int*)alloc((size_t)NB * 4);
    int* cursor = (int*)alloc((size_t)NB * 4);
    int* cnt3   = (int*)alloc((size_t)N_VOX * 4);
    int* cur3   = (int*)alloc((size_t)N_VOX * 4);
    size_t zlen = (size_t)((char*)cur3 - (char*)cnt) + (size_t)N_VOX * 4;
    int* offs   = (int*)alloc((size_t)(NB + 1) * 4);
    int* ss3    = (int*)alloc((size_t)(N_VOX + 1) * 4);
    int* cdoffs = (int*)alloc((size_t)(NB + 1) * 4);
    float* sbp1 = (float*)alloc(128 * 4);
    float* sbp2 = (float*)alloc(128 * 4);
    unsigned short* wb1 = (unsigned short*)alloc((size_t)WBN * 2);
    unsigned short* wb2 = (unsigned short*)alloc((size_t)WBN * 2);
    unsigned int* payload = (unsigned int*)alloc((size_t)KM * 4);
    unsigned int* perm    = (unsigned int*)alloc((size_t)KM * 4);
    unsigned long long* cdesc = (unsigned long long*)alloc((size_t)CDCAP * 8);
    unsigned short* xb = (unsigned short*)alloc((size_t)N_VOX * C_CH * 2);
    unsigned short* hb = (unsigned short*)alloc((size_t)N_VOX * C_CH * 2);
    size_t baseB = off;

    // group count by workspace budget: Y holds one group of bf16 rows (+ dummy region)
    const int ngs[4]  = {8, 16, 32, 64};
    const int caps[4] = {345000, 175000, 90000, 47000};
    int NG = 64, CAP = 47000;
    for (int i = 0; i < 4; ++i) {
        size_t need = baseB + ((size_t)caps[i] + 80) * 128;
        if (ws_size >= need) { NG = ngs[i]; CAP = caps[i]; break; }
    }
    unsigned int* Y = (unsigned int*)alloc(((size_t)CAP + 80) * 128);
    const int TPG = (NT + NG - 1) / NG;

    hipMemsetAsync(cnt, 0, zlen, stream);

    const long TOT = (long)N_VOX * C_CH + 2 * WBN + 128 + KM;
    prep_kernel<<<(int)((TOT + 255) / 256), 256, 0, stream>>>(
        x, w1, w2, g1, b1, m1, v1, g2, b2, m2, v2, in_map, out_map,
        xb, wb1, wb2, sbp1, sbp2, cnt, cnt3);

    scan_kernel<<<1, 1024, 0, stream>>>(cnt, offs, NB, 0);
    scan_kernel<<<1, 1024, 0, stream>>>(cnt3, ss3, N_VOX, 0);
    scan_kernel<<<1, 1024, 0, stream>>>(cnt, cdoffs, NB, 1);

    scatter_kernel<<<(KM + 255) / 256, 256, 0, stream>>>(
        in_map, out_map, offs, cursor, ss3, cur3, payload, perm);

    cdescb_kernel<<<(NB + 255) / 256, 256, 0, stream>>>(cnt, offs, cdoffs, cdesc);

    // worst-case chunk count per group -> grid for computeY (early-exit inside)
    const int capC = CAP / 16 + TPG * K_OFF + 8;
    const int cyb = (capC + 3) / 4;

    for (int L = 0; L < 2; ++L) {
        const unsigned short* src = (L == 0) ? xb : hb;
        const unsigned short* wbL = (L == 0) ? wb1 : wb2;
        const float* sbpL = (L == 0) ? sbp1 : sbp2;
        for (int g = 0; g < NG; ++g) {
            int tg0 = g * TPG;
            int tg1 = tg0 + TPG; if (tg1 > NT) tg1 = NT;
            if (tg0 >= tg1) break;
            computeY_kernel<<<cyb, 256, 0, stream>>>(
                src, wbL, payload, perm, cdesc,
                cdoffs + (size_t)tg0 * K_OFF, cdoffs + (size_t)tg1 * K_OFF,
                ss3 + (size_t)tg0 * TILE, Y, CAP);
            int obase = tg0 * TILE, oend = tg1 * TILE;
            int rblocks = (oend - obase + 31) / 32;
            if (L == 0)
                reduce_kernel<0><<<rblocks, 256, 0, stream>>>(
                    Y, ss3, ss3 + (size_t)tg0 * TILE, sbpL, nullptr, hb, obase, oend);
            else
                reduce_kernel<1><<<rblocks, 256, 0, stream>>>(
                    Y, ss3, ss3 + (size_t)tg0 * TILE, sbpL, x, d_out, obase, oend);
        }
    }
}

// Round 7
// 1040.176 us; speedup vs baseline: 3.3818x; 1.6278x over previous
//
#include <hip/hip_runtime.h>
#include <stdint.h>

// Problem constants
#define N_VOX    200000
#define C_CH     64
#define K_OFF    27
#define M_PAIRS  100000
#define KM       (K_OFF * M_PAIRS)          // 2,700,000 pairs
#define TILE     64                         // output voxels per tile (o>>6)
#define NT       (N_VOX / TILE)             // 3125 tiles exactly
#define NB       (NT * K_OFF)               // 84375 (tile,k) buckets
#define WBN      (K_OFF * 4096)             // 110592 weight elems per layer
#define EPS_BN   1e-5f
#define CDCAP    (KM / 16 + NB + 64)        // max total chunks

// hierarchical scan geometry
#define SCHUNK   2048
#define NBLK1    ((NB + SCHUNK - 1) / SCHUNK)      // 42
#define NBLK2    ((N_VOX + SCHUNK - 1) / SCHUNK)   // 98
#define PQ1      0
#define PQ2      128
#define PQ3      256

typedef __attribute__((ext_vector_type(8))) short   short8_t;  // 8 x bf16
typedef __attribute__((ext_vector_type(4))) float   f32x4;

__device__ __forceinline__ unsigned short f2bf(float f) {
    union { float f; unsigned u; } v; v.f = f;
    unsigned r = v.u + 0x7FFFu + ((v.u >> 16) & 1u);   // RTNE
    return (unsigned short)(r >> 16);
}
__device__ __forceinline__ float bf2f(unsigned u16) {
    union { unsigned u; float f; } v; v.u = u16 << 16;
    return v.f;
}
// hb/Y flat bf16 index cs -> standard channel (position layout)
__device__ __forceinline__ int pmap(int cs) {
    int p = cs >> 1, h = cs & 1;
    return (p & 3) * 16 + (p >> 2) * 2 + h;
}

// ---------- prep: xb convert, w1 (std) / w2 (PMAP-Cin) B-frag swizzle, BN fold (position order), dual hist ----------
__global__ void prep_kernel(const float* __restrict__ x,
                            const float* __restrict__ w1, const float* __restrict__ w2,
                            const float* __restrict__ g1, const float* __restrict__ b1,
                            const float* __restrict__ m1, const float* __restrict__ v1,
                            const float* __restrict__ g2, const float* __restrict__ b2,
                            const float* __restrict__ m2, const float* __restrict__ v2,
                            const int* __restrict__ in_map, const int* __restrict__ out_map,
                            unsigned short* __restrict__ xb,
                            unsigned short* __restrict__ wb1, unsigned short* __restrict__ wb2,
                            float* __restrict__ sbp1, float* __restrict__ sbp2,
                            int* __restrict__ cnt, int* __restrict__ cnt3)
{
    long i = (long)blockIdx.x * blockDim.x + threadIdx.x;
    const long XBN = (long)N_VOX * C_CH;
    if (i < XBN) { xb[i] = f2bf(x[i]); return; }
    long j = i - XBN;
    if (j < 2 * WBN) {
        int isw2 = j >= WBN;
        int o = (int)(isw2 ? j - WBN : j);
        int k   = o >> 12;
        int rem = o & 4095;
        int t  = rem >> 11;
        int sl = (rem >> 9) & 3;
        int d  = (rem >> 3) & 63;
        int jj = rem & 7;
        int cs = t * 32 + sl * 8 + jj;      // A k-slot (flat bf16 index of input row)
        if (!isw2) wb1[o] = f2bf(w1[k * 4096 + cs * 64 + d]);
        else       wb2[o] = f2bf(w2[k * 4096 + pmap(cs) * 64 + d]);  // hb is position-permuted
        return;
    }
    j -= 2 * WBN;
    if (j < 128) {
        int L = (int)(j >= 64);
        int ch = (int)(j & 63);
        float gv = L ? g2[ch] : g1[ch];
        float vv = L ? v2[ch] : v1[ch];
        float mv = L ? m2[ch] : m1[ch];
        float bv = L ? b2[ch] : b1[ch];
        float s = gv * rsqrtf(vv + EPS_BN);
        float sh = bv - mv * s;
        int n = ch >> 4, rem = ch & 15, m = rem >> 1, h = rem & 1;
        int idx = 2 * (m * 4 + n) + h;      // position-mapped slot
        float* sbp = L ? sbp2 : sbp1;
        sbp[idx] = s; sbp[64 + idx] = sh;
        return;
    }
    j -= 128;
    if (j < KM) {
        int p = (int)j;
        int k = p / M_PAIRS;
        int o = out_map[p];
        atomicAdd(&cnt[(o >> 6) * K_OFF + k], 1);
        atomicAdd(&cnt3[o], 1);
    }
}

// ---------------- hierarchical scan: A = chunk partials ----------------
__global__ __launch_bounds__(256) void scanA_kernel(const int* __restrict__ cnt,
                                                    const int* __restrict__ cnt3,
                                                    int* __restrict__ part)
{
    __shared__ int lds[256];
    __shared__ int lds2[256];
    int b = blockIdx.x, t = threadIdx.x;
    if (b < NBLK1) {
        int base = b * SCHUNK;
        int sraw = 0, sc16 = 0;
        for (int i = t; i < SCHUNK; i += 256) {
            int idx = base + i;
            if (idx < NB) { int c = cnt[idx]; sraw += c; sc16 += (c + 15) >> 4; }
        }
        lds[t] = sraw; lds2[t] = sc16;
        __syncthreads();
        for (int d = 128; d > 0; d >>= 1) {
            if (t < d) { lds[t] += lds[t + d]; lds2[t] += lds2[t + d]; }
            __syncthreads();
        }
        if (t == 0) { part[PQ1 + b] = lds[0]; part[PQ2 + b] = lds2[0]; }
    } else {
        int bb = b - NBLK1;
        int base = bb * SCHUNK;
        int s = 0;
        for (int i = t; i < SCHUNK; i += 256) {
            int idx = base + i;
            if (idx < N_VOX) s += cnt3[idx];
        }
        lds[t] = s;
        __syncthreads();
        for (int d = 128; d > 0; d >>= 1) {
            if (t < d) lds[t] += lds[t + d];
            __syncthreads();
        }
        if (t == 0) part[PQ3 + bb] = lds[0];
    }
}

// ---------------- hierarchical scan: B = exclusive scan of partials (3 segments) ----------------
__global__ __launch_bounds__(128) void scanB_kernel(int* __restrict__ part) {
    __shared__ int lds[128];
    int g = blockIdx.x, t = threadIdx.x;
    int base = (g == 0) ? PQ1 : (g == 1) ? PQ2 : PQ3;
    int n    = (g < 2) ? NBLK1 : NBLK2;
    int v = (t < n) ? part[base + t] : 0;
    lds[t] = v;
    __syncthreads();
    for (int d = 1; d < 128; d <<= 1) {
        int u = (t >= d) ? lds[t - d] : 0;
        __syncthreads();
        lds[t] += u;
        __syncthreads();
    }
    if (t < n) part[base + t] = lds[t] - v;   // exclusive base per chunk
}

// ---------------- hierarchical scan: C = chunk-local scan + base, write outputs ----------------
__global__ __launch_bounds__(256) void scanC_kernel(const int* __restrict__ cnt,
                                                    const int* __restrict__ cnt3,
                                                    const int* __restrict__ part,
                                                    int* __restrict__ offs,
                                                    int* __restrict__ cdoffs,
                                                    int* __restrict__ ss3)
{
    __shared__ int lds[256], lds2[256];
    int b = blockIdx.x, t = threadIdx.x;
    if (b < NBLK1) {
        int i0 = b * SCHUNK + t * 8;
        int c[8]; int sraw = 0, sc16 = 0;
        #pragma unroll
        for (int j = 0; j < 8; ++j) {
            int idx = i0 + j;
            c[j] = (idx < NB) ? cnt[idx] : 0;
            sraw += c[j]; sc16 += (c[j] + 15) >> 4;
        }
        int vr = sraw, vc = sc16;
        lds[t] = vr; lds2[t] = vc;
        __syncthreads();
        for (int d = 1; d < 256; d <<= 1) {
            int ur = (t >= d) ? lds[t - d] : 0;
            int uc = (t >= d) ? lds2[t - d] : 0;
            __syncthreads();
            lds[t] += ur; lds2[t] += uc;
            __syncthreads();
        }
        int braw = part[PQ1 + b] + lds[t] - vr;
        int bc16 = part[PQ2 + b] + lds2[t] - vc;
        #pragma unroll
        for (int j = 0; j < 8; ++j) {
            int idx = i0 + j;
            if (idx < NB) { offs[idx] = braw; cdoffs[idx] = bc16; }
            braw += c[j]; bc16 += (c[j] + 15) >> 4;
        }
        if (b == NBLK1 - 1 && t == 255) { offs[NB] = braw; cdoffs[NB] = bc16; }
    } else {
        int bb = b - NBLK1;
        int i0 = bb * SCHUNK + t * 8;
        int c[8]; int s = 0;
        #pragma unroll
        for (int j = 0; j < 8; ++j) {
            int idx = i0 + j;
            c[j] = (idx < N_VOX) ? cnt3[idx] : 0;
            s += c[j];
        }
        int v = s;
        lds[t] = v;
        __syncthreads();
        for (int d = 1; d < 256; d <<= 1) {
            int u = (t >= d) ? lds[t - d] : 0;
            __syncthreads();
            lds[t] += u;
            __syncthreads();
        }
        int bs = part[PQ3 + bb] + lds[t] - v;
        #pragma unroll
        for (int j = 0; j < 8; ++j) {
            int idx = i0 + j;
            if (idx < N_VOX) ss3[idx] = bs;
            bs += c[j];
        }
        if (bb == NBLK2 - 1 && t == 255) ss3[N_VOX] = bs;
    }
}

// ---------- scatter both orders: payload[pos]=iidx ((tile,k)-sorted), perm[pos]=pos3 (o-sorted rank) ----------
__global__ void scatter_kernel(const int* __restrict__ in_map, const int* __restrict__ out_map,
                               const int* __restrict__ offs, int* __restrict__ cursor,
                               const int* __restrict__ ss3, int* __restrict__ cur3,
                               unsigned int* __restrict__ payload, unsigned int* __restrict__ perm)
{
    int p = blockIdx.x * 256 + threadIdx.x;
    if (p >= KM) return;
    int k = p / M_PAIRS;
    int o = out_map[p];
    int key = (o >> 6) * K_OFF + k;
    int pos = offs[key] + atomicAdd(&cursor[key], 1);
    payload[pos] = (unsigned)in_map[p];
    int pos3 = ss3[o] + atomicAdd(&cur3[o], 1);
    perm[pos] = (unsigned)pos3;
}

// ---------- build global chunk descriptors: k | pbase<<5 | pend<<27 ----------
__global__ void cdescb_kernel(const int* __restrict__ cnt, const int* __restrict__ offs,
                              const int* __restrict__ cdoffs, unsigned long long* __restrict__ cdesc)
{
    int b = blockIdx.x * 256 + threadIdx.x;
    if (b >= NB) return;
    int k = b % K_OFF;
    int c0 = cdoffs[b];
    int nchunk = cdoffs[b + 1] - c0;
    int base = offs[b];
    int end  = offs[b + 1];
    for (int i = 0; i < nchunk; ++i)
        cdesc[c0 + i] = (unsigned long long)k
                      | ((unsigned long long)(base + 16 * i) << 5)
                      | ((unsigned long long)end << 27);
}

// ---------- computeY: one chunk per wave; gather 16 rows, 8 MFMA, repack, random row write ----------
__global__ __launch_bounds__(256) void computeY_kernel(
    const unsigned short* __restrict__ xin,     // bf16 rows [N][64] (xb std / hb position-layout)
    const unsigned short* __restrict__ wb,      // pre-swizzled bf16 weights
    const unsigned int* __restrict__ payload,
    const unsigned int* __restrict__ perm,
    const unsigned long long* __restrict__ cdesc,
    const int* __restrict__ csp,                // &cdoffs[tg0*27]
    const int* __restrict__ cep,                // &cdoffs[tg1*27]
    const int* __restrict__ ygbp,               // &ss3[tg0*64]
    unsigned int* __restrict__ Y,               // rows of 32 u32 (bf16 pairs, position layout)
    int ycap)                                   // real rows capacity; dummies at ycap+8+
{
    int c = csp[0] + blockIdx.x * 4 + (threadIdx.x >> 6);
    if (c >= cep[0]) return;
    unsigned long long d = cdesc[c];
    int k     = (int)(d & 31);
    int pbase = (int)((d >> 5) & 0x3FFFFF);
    int pend  = (int)(d >> 27);
    int ygb = ygbp[0];
    int lane  = threadIdx.x & 63;
    int r     = lane & 15;
    int sfour = lane >> 4;
    int par   = lane & 1;

    int ii = pbase + r;
    bool real = ii < pend;
    int pidx = real ? ii : pbase;
    unsigned iidx = payload[pidx];
    int yr;
    if (real) {
        yr = (int)perm[pidx] - ygb;
        if (yr > ycap) yr = ycap;               // overflow guard
    } else {
        yr = ycap + 8 + (c & 63);               // spread dummy rows
    }

    const short8_t* xrow = (const short8_t*)(xin + (size_t)iidx * 64);
    short8_t A0 = xrow[sfour];
    short8_t A1 = xrow[4 + sfour];
    const short8_t* wbk = (const short8_t*)(wb + k * 4096);

    f32x4 acc[4] = {{0,0,0,0},{0,0,0,0},{0,0,0,0},{0,0,0,0}};
    #pragma unroll
    for (int n = 0; n < 4; ++n) {
        acc[n] = __builtin_amdgcn_mfma_f32_16x16x32_bf16(A0, wbk[sfour * 64 + n * 16 + r], acc[n], 0, 0, 0);
        acc[n] = __builtin_amdgcn_mfma_f32_16x16x32_bf16(A1, wbk[(4 + sfour) * 64 + n * 16 + r], acc[n], 0, 0, 0);
    }

    // repack D (col=n*16+r, row=sfour*4+j) into bf16 Y rows; lane-pair exchange packs ch pairs
    #pragma unroll
    for (int jj = 0; jj < 4; jj += 2) {
        uint4 w;
        unsigned* wp = (unsigned*)&w;
        #pragma unroll
        for (int n = 0; n < 4; ++n) {
            float mine = par ? acc[n][jj + 1] : acc[n][jj];
            float send = par ? acc[n][jj]     : acc[n][jj + 1];
            float t = __shfl_xor(send, 1, 64);
            float lo = par ? t : mine;
            float hi = par ? mine : t;
            wp[n] = (unsigned)f2bf(lo) | ((unsigned)f2bf(hi) << 16);
        }
        int Rw = sfour * 4 + jj + par;          // pair slot whose row this lane packs
        int yrow = __shfl(yr, Rw, 64);
        ((uint4*)Y)[(size_t)yrow * 8 + (r >> 1)] = w;
    }
}

// ---------- reduce: segmented sum of consecutive Y rows per output + BN(+relu)(+residual) ----------
template<int LAYER>
__global__ __launch_bounds__(256) void reduce_kernel(
    const unsigned int* __restrict__ Y,
    const int* __restrict__ ss3,
    const int* __restrict__ ygbp,
    const float* __restrict__ sbp,              // [0:64) scale, [64:128) shift (position order)
    const float* __restrict__ xres,             // LAYER==1 residual (std layout)
    void* __restrict__ outp,                    // L0: hb (bf16 position layout); L1: f32 std
    int obase, int oend)
{
    int w = blockIdx.x * 4 + (threadIdx.x >> 6);
    int lane = threadIdx.x & 63;
    int q = lane & 7;
    int og = obase + w * 8 + (lane >> 3);
    if (og >= oend) return;
    int ygb = ygbp[0];
    int s0 = ss3[og], s1 = ss3[og + 1];
    int i0 = s0 - ygb, cnt = s1 - s0;

    float sum[8] = {0.f,0.f,0.f,0.f,0.f,0.f,0.f,0.f};
    for (int i = 0; i < cnt; ++i) {
        uint4 v = ((const uint4*)Y)[(size_t)(i0 + i) * 8 + q];
        const unsigned* vp = (const unsigned*)&v;
        #pragma unroll
        for (int t = 0; t < 4; ++t) {
            sum[2 * t]     += bf2f(vp[t] & 0xFFFFu);
            sum[2 * t + 1] += bf2f(vp[t] >> 16);
        }
    }

    const float2* sc2 = (const float2*)sbp;
    const float2* sh2 = (const float2*)(sbp + 64);
    if (LAYER == 0) {
        uint4 o4;
        unsigned* op = (unsigned*)&o4;
        #pragma unroll
        for (int t = 0; t < 4; ++t) {
            int p = q * 4 + t;
            float a = sum[2 * t]     * sc2[p].x + sh2[p].x;
            float b = sum[2 * t + 1] * sc2[p].y + sh2[p].y;
            a = a > 0.f ? a : 0.f;
            b = b > 0.f ? b : 0.f;
            op[t] = (unsigned)f2bf(a) | ((unsigned)f2bf(b) << 16);
        }
        ((uint4*)outp)[(size_t)og * 8 + q] = o4;            // hb row, position layout
    } else {
        float* out = (float*)outp;
        #pragma unroll
        for (int t = 0; t < 4; ++t) {
            int p = q * 4 + t;
            int ch0 = t * 16 + 2 * q;                        // std channel of (p, h=0)
            float2 xr = *(const float2*)(xres + (size_t)og * 64 + ch0);
            float a = sum[2 * t]     * sc2[p].x + sh2[p].x + xr.x;
            float b = sum[2 * t + 1] * sc2[p].y + sh2[p].y + xr.y;
            a = a > 0.f ? a : 0.f;
            b = b > 0.f ? b : 0.f;
            *(float2*)(out + (size_t)og * 64 + ch0) = make_float2(a, b);
        }
    }
}

// ---------------- launch ----------------
extern "C" void kernel_launch(void* const* d_in, const int* in_sizes, int n_in,
                              void* d_out, int out_size, void* d_ws, size_t ws_size,
                              hipStream_t stream)
{
    const float* x  = (const float*)d_in[0];
    const float* w1 = (const float*)d_in[1];
    const float* w2 = (const float*)d_in[2];
    const float* g1 = (const float*)d_in[3];
    const float* b1 = (const float*)d_in[4];
    const float* m1 = (const float*)d_in[5];
    const float* v1 = (const float*)d_in[6];
    const float* g2 = (const float*)d_in[7];
    const float* b2 = (const float*)d_in[8];
    const float* m2 = (const float*)d_in[9];
    const float* v2 = (const float*)d_in[10];
    const int* in_map  = (const int*)d_in[11];
    const int* out_map = (const int*)d_in[12];

    char* ws = (char*)d_ws;
    size_t off = 0;
    auto alloc = [&](size_t bytes) -> void* {
        void* p = ws + off;
        off = (off + bytes + 255) & ~(size_t)255;
        return p;
    };
    // zeroed region: cnt, cursor, cnt3, cur3 (contiguous)
    int* cnt    = (int*)alloc((size_t)NB * 4);
    int* cursor = (int*)alloc((size_t)NB * 4);
    int* cnt3   = (int*)alloc((size_t)N_VOX * 4);
    int* cur3   = (int*)alloc((size_t)N_VOX * 4);
    size_t zlen = (size_t)((char*)cur3 - (char*)cnt) + (size_t)N_VOX * 4;
    int* offs   = (int*)alloc((size_t)(NB + 1) * 4);
    int* ss3    = (int*)alloc((size_t)(N_VOX + 1) * 4);
    int* cdoffs = (int*)alloc((size_t)(NB + 1) * 4);
    int* part   = (int*)alloc(512 * 4);
    float* sbp1 = (float*)alloc(128 * 4);
    float* sbp2 = (float*)alloc(128 * 4);
    unsigned short* wb1 = (unsigned short*)alloc((size_t)WBN * 2);
    unsigned short* wb2 = (unsigned short*)alloc((size_t)WBN * 2);
    unsigned int* payload = (unsigned int*)alloc((size_t)KM * 4);
    unsigned int* perm    = (unsigned int*)alloc((size_t)KM * 4);
    unsigned long long* cdesc = (unsigned long long*)alloc((size_t)CDCAP * 8);
    unsigned short* xb = (unsigned short*)alloc((size_t)N_VOX * C_CH * 2);
    unsigned short* hb = (unsigned short*)alloc((size_t)N_VOX * C_CH * 2);
    size_t baseB = off;

    // group count by workspace budget: Y holds one group of bf16 rows (+ dummy region)
    const int ngs[4]  = {8, 16, 32, 64};
    const int caps[4] = {345000, 175000, 90000, 47000};
    int NG = 64, CAP = 47000;
    for (int i = 0; i < 4; ++i) {
        size_t need = baseB + ((size_t)caps[i] + 80) * 128;
        if (ws_size >= need) { NG = ngs[i]; CAP = caps[i]; break; }
    }
    unsigned int* Y = (unsigned int*)alloc(((size_t)CAP + 80) * 128);
    const int TPG = (NT + NG - 1) / NG;

    hipMemsetAsync(cnt, 0, zlen, stream);

    const long TOT = (long)N_VOX * C_CH + 2 * WBN + 128 + KM;
    prep_kernel<<<(int)((TOT + 255) / 256), 256, 0, stream>>>(
        x, w1, w2, g1, b1, m1, v1, g2, b2, m2, v2, in_map, out_map,
        xb, wb1, wb2, sbp1, sbp2, cnt, cnt3);

    scanA_kernel<<<NBLK1 + NBLK2, 256, 0, stream>>>(cnt, cnt3, part);
    scanB_kernel<<<3, 128, 0, stream>>>(part);
    scanC_kernel<<<NBLK1 + NBLK2, 256, 0, stream>>>(cnt, cnt3, part, offs, cdoffs, ss3);

    scatter_kernel<<<(KM + 255) / 256, 256, 0, stream>>>(
        in_map, out_map, offs, cursor, ss3, cur3, payload, perm);

    cdescb_kernel<<<(NB + 255) / 256, 256, 0, stream>>>(cnt, offs, cdoffs, cdesc);

    // worst-case chunk count per group -> grid for computeY (early-exit inside)
    const int capC = CAP / 16 + TPG * K_OFF + 8;
    const int cyb = (capC + 3) / 4;

    for (int L = 0; L < 2; ++L) {
        const unsigned short* src = (L == 0) ? xb : hb;
        const unsigned short* wbL = (L == 0) ? wb1 : wb2;
        const float* sbpL = (L == 0) ? sbp1 : sbp2;
        for (int g = 0; g < NG; ++g) {
            int tg0 = g * TPG;
            int tg1 = tg0 + TPG; if (tg1 > NT) tg1 = NT;
            if (tg0 >= tg1) break;
            computeY_kernel<<<cyb, 256, 0, stream>>>(
                src, wbL, payload, perm, cdesc,
                cdoffs + (size_t)tg0 * K_OFF, cdoffs + (size_t)tg1 * K_OFF,
                ss3 + (size_t)tg0 * TILE, Y, CAP);
            int obase = tg0 * TILE, oend = tg1 * TILE;
            int rblocks = (oend - obase + 31) / 32;
            if (L == 0)
                reduce_kernel<0><<<rblocks, 256, 0, stream>>>(
                    Y, ss3, ss3 + (size_t)tg0 * TILE, sbpL, nullptr, hb, obase, oend);
            else
                reduce_kernel<1><<<rblocks, 256, 0, stream>>>(
                    Y, ss3, ss3 + (size_t)tg0 * TILE, sbpL, x, d_out, obase, oend);
        }
    }
}

// Round 8
// 946.269 us; speedup vs baseline: 3.7175x; 1.0992x over previous
//
#include <hip/hip_runtime.h>
#include <stdint.h>

// Problem constants
#define N_VOX    200000
#define C_CH     64
#define K_OFF    27
#define M_PAIRS  100000
#define KM       (K_OFF * M_PAIRS)          // 2,700,000 pairs
#define TILE     64                         // output voxels per tile (o>>6)
#define NT       (N_VOX / TILE)             // 3125 tiles exactly
#define NB       (NT * K_OFF)               // 84375 (tile,k) buckets
#define WBN      (K_OFF * 4096)             // 110592 weight elems per layer
#define EPS_BN   1e-5f
#define CDCAP    (KM / 16 + NB + 64)        // max total chunks

// hierarchical scan geometry
#define SCHUNK   2048
#define NBLK1    ((NB + SCHUNK - 1) / SCHUNK)      // 42
#define NBLK2    ((N_VOX + SCHUNK - 1) / SCHUNK)   // 98
#define PQ1      0
#define PQ2      128
#define PQ3      256

typedef __attribute__((ext_vector_type(8))) short   short8_t;  // 8 x bf16
typedef __attribute__((ext_vector_type(4))) float   f32x4;

__device__ __forceinline__ unsigned short f2bf(float f) {
    union { float f; unsigned u; } v; v.f = f;
    unsigned r = v.u + 0x7FFFu + ((v.u >> 16) & 1u);   // RTNE
    return (unsigned short)(r >> 16);
}
__device__ __forceinline__ float bf2f(unsigned u16) {
    union { unsigned u; float f; } v; v.u = u16 << 16;
    return v.f;
}
// hb/Y flat bf16 index cs -> standard channel (position layout)
__device__ __forceinline__ int pmap(int cs) {
    int p = cs >> 1, h = cs & 1;
    return (p & 3) * 16 + (p >> 2) * 2 + h;
}

// ---------- prep: xb convert, w1 (std) / w2 (PMAP-Cin) B-frag swizzle, BN fold (position order), dual hist ----------
__global__ void prep_kernel(const float* __restrict__ x,
                            const float* __restrict__ w1, const float* __restrict__ w2,
                            const float* __restrict__ g1, const float* __restrict__ b1,
                            const float* __restrict__ m1, const float* __restrict__ v1,
                            const float* __restrict__ g2, const float* __restrict__ b2,
                            const float* __restrict__ m2, const float* __restrict__ v2,
                            const int* __restrict__ out_map,
                            unsigned short* __restrict__ xb,
                            unsigned short* __restrict__ wb1, unsigned short* __restrict__ wb2,
                            float* __restrict__ sbp1, float* __restrict__ sbp2,
                            int* __restrict__ cnt, int* __restrict__ cnt3)
{
    long i = (long)blockIdx.x * blockDim.x + threadIdx.x;
    const long XBN = (long)N_VOX * C_CH;
    if (i < XBN) { xb[i] = f2bf(x[i]); return; }
    long j = i - XBN;
    if (j < 2 * WBN) {
        int isw2 = j >= WBN;
        int o = (int)(isw2 ? j - WBN : j);
        int k   = o >> 12;
        int rem = o & 4095;
        int t  = rem >> 11;
        int sl = (rem >> 9) & 3;
        int d  = (rem >> 3) & 63;
        int jj = rem & 7;
        int cs = t * 32 + sl * 8 + jj;      // A k-slot (flat bf16 index of input row)
        if (!isw2) wb1[o] = f2bf(w1[k * 4096 + cs * 64 + d]);
        else       wb2[o] = f2bf(w2[k * 4096 + pmap(cs) * 64 + d]);  // hb is position-permuted
        return;
    }
    j -= 2 * WBN;
    if (j < 128) {
        int L = (int)(j >= 64);
        int ch = (int)(j & 63);
        float gv = L ? g2[ch] : g1[ch];
        float vv = L ? v2[ch] : v1[ch];
        float mv = L ? m2[ch] : m1[ch];
        float bv = L ? b2[ch] : b1[ch];
        float s = gv * rsqrtf(vv + EPS_BN);
        float sh = bv - mv * s;
        int n = ch >> 4, rem = ch & 15, m = rem >> 1, h = rem & 1;
        int idx = 2 * (m * 4 + n) + h;      // position-mapped slot
        float* sbp = L ? sbp2 : sbp1;
        sbp[idx] = s; sbp[64 + idx] = sh;
        return;
    }
    j -= 128;
    if (j < KM) {
        int p = (int)j;
        int k = p / M_PAIRS;
        int o = out_map[p];
        atomicAdd(&cnt[(o >> 6) * K_OFF + k], 1);
        atomicAdd(&cnt3[o], 1);
    }
}

// ---------------- hierarchical scan: A = chunk partials ----------------
__global__ __launch_bounds__(256) void scanA_kernel(const int* __restrict__ cnt,
                                                    const int* __restrict__ cnt3,
                                                    int* __restrict__ part)
{
    __shared__ int lds[256];
    __shared__ int lds2[256];
    int b = blockIdx.x, t = threadIdx.x;
    if (b < NBLK1) {
        int base = b * SCHUNK;
        int sraw = 0, sc16 = 0;
        for (int i = t; i < SCHUNK; i += 256) {
            int idx = base + i;
            if (idx < NB) { int c = cnt[idx]; sraw += c; sc16 += (c + 15) >> 4; }
        }
        lds[t] = sraw; lds2[t] = sc16;
        __syncthreads();
        for (int d = 128; d > 0; d >>= 1) {
            if (t < d) { lds[t] += lds[t + d]; lds2[t] += lds2[t + d]; }
            __syncthreads();
        }
        if (t == 0) { part[PQ1 + b] = lds[0]; part[PQ2 + b] = lds2[0]; }
    } else {
        int bb = b - NBLK1;
        int base = bb * SCHUNK;
        int s = 0;
        for (int i = t; i < SCHUNK; i += 256) {
            int idx = base + i;
            if (idx < N_VOX) s += cnt3[idx];
        }
        lds[t] = s;
        __syncthreads();
        for (int d = 128; d > 0; d >>= 1) {
            if (t < d) lds[t] += lds[t + d];
            __syncthreads();
        }
        if (t == 0) part[PQ3 + bb] = lds[0];
    }
}

// ---------------- hierarchical scan: B = exclusive scan of partials (3 segments) ----------------
__global__ __launch_bounds__(128) void scanB_kernel(int* __restrict__ part) {
    __shared__ int lds[128];
    int g = blockIdx.x, t = threadIdx.x;
    int base = (g == 0) ? PQ1 : (g == 1) ? PQ2 : PQ3;
    int n    = (g < 2) ? NBLK1 : NBLK2;
    int v = (t < n) ? part[base + t] : 0;
    lds[t] = v;
    __syncthreads();
    for (int d = 1; d < 128; d <<= 1) {
        int u = (t >= d) ? lds[t - d] : 0;
        __syncthreads();
        lds[t] += u;
        __syncthreads();
    }
    if (t < n) part[base + t] = lds[t] - v;   // exclusive base per chunk
}

// ---------------- hierarchical scan: C = chunk-local scan + base, write outputs ----------------
__global__ __launch_bounds__(256) void scanC_kernel(const int* __restrict__ cnt,
                                                    const int* __restrict__ cnt3,
                                                    const int* __restrict__ part,
                                                    int* __restrict__ offs,
                                                    int* __restrict__ cdoffs,
                                                    int* __restrict__ ss3)
{
    __shared__ int lds[256], lds2[256];
    int b = blockIdx.x, t = threadIdx.x;
    if (b < NBLK1) {
        int i0 = b * SCHUNK + t * 8;
        int c[8]; int sraw = 0, sc16 = 0;
        #pragma unroll
        for (int j = 0; j < 8; ++j) {
            int idx = i0 + j;
            c[j] = (idx < NB) ? cnt[idx] : 0;
            sraw += c[j]; sc16 += (c[j] + 15) >> 4;
        }
        int vr = sraw, vc = sc16;
        lds[t] = vr; lds2[t] = vc;
        __syncthreads();
        for (int d = 1; d < 256; d <<= 1) {
            int ur = (t >= d) ? lds[t - d] : 0;
            int uc = (t >= d) ? lds2[t - d] : 0;
            __syncthreads();
            lds[t] += ur; lds2[t] += uc;
            __syncthreads();
        }
        int braw = part[PQ1 + b] + lds[t] - vr;
        int bc16 = part[PQ2 + b] + lds2[t] - vc;
        #pragma unroll
        for (int j = 0; j < 8; ++j) {
            int idx = i0 + j;
            if (idx < NB) { offs[idx] = braw; cdoffs[idx] = bc16; }
            braw += c[j]; bc16 += (c[j] + 15) >> 4;
        }
        if (b == NBLK1 - 1 && t == 255) { offs[NB] = braw; cdoffs[NB] = bc16; }
    } else {
        int bb = b - NBLK1;
        int i0 = bb * SCHUNK + t * 8;
        int c[8]; int s = 0;
        #pragma unroll
        for (int j = 0; j < 8; ++j) {
            int idx = i0 + j;
            c[j] = (idx < N_VOX) ? cnt3[idx] : 0;
            s += c[j];
        }
        int v = s;
        lds[t] = v;
        __syncthreads();
        for (int d = 1; d < 256; d <<= 1) {
            int u = (t >= d) ? lds[t - d] : 0;
            __syncthreads();
            lds[t] += u;
            __syncthreads();
        }
        int bs = part[PQ3 + bb] + lds[t] - v;
        #pragma unroll
        for (int j = 0; j < 8; ++j) {
            int idx = i0 + j;
            if (idx < N_VOX) ss3[idx] = bs;
            bs += c[j];
        }
        if (bb == NBLK2 - 1 && t == 255) ss3[N_VOX] = bs;
    }
}

// ---------- scatter: ONE packed 8B write per pair: pp[pos] = iidx | pos3<<32 ----------
__global__ void scatter_kernel(const int* __restrict__ in_map, const int* __restrict__ out_map,
                               const int* __restrict__ offs, int* __restrict__ cursor,
                               const int* __restrict__ ss3, int* __restrict__ cur3,
                               unsigned long long* __restrict__ pp)
{
    int p = blockIdx.x * 256 + threadIdx.x;
    if (p >= KM) return;
    int k = p / M_PAIRS;
    int o = out_map[p];
    int key = (o >> 6) * K_OFF + k;
    int pos = offs[key] + atomicAdd(&cursor[key], 1);
    int pos3 = ss3[o] + atomicAdd(&cur3[o], 1);
    pp[pos] = (unsigned long long)(unsigned)in_map[p]
            | ((unsigned long long)(unsigned)pos3 << 32);
}

// ---------- build global chunk descriptors: k | pbase<<5 | pend<<27 ----------
__global__ void cdescb_kernel(const int* __restrict__ cnt, const int* __restrict__ offs,
                              const int* __restrict__ cdoffs, unsigned long long* __restrict__ cdesc)
{
    int b = blockIdx.x * 256 + threadIdx.x;
    if (b >= NB) return;
    int k = b % K_OFF;
    int c0 = cdoffs[b];
    int nchunk = cdoffs[b + 1] - c0;
    int base = offs[b];
    int end  = offs[b + 1];
    for (int i = 0; i < nchunk; ++i)
        cdesc[c0 + i] = (unsigned long long)k
                      | ((unsigned long long)(base + 16 * i) << 5)
                      | ((unsigned long long)end << 27);
}

// ---------- computeY: one chunk per wave; gather 16 rows, 8 MFMA, repack, random row write ----------
__global__ __launch_bounds__(256) void computeY_kernel(
    const unsigned short* __restrict__ xin,     // bf16 rows [N][64] (xb std / hb position-layout)
    const unsigned short* __restrict__ wb,      // pre-swizzled bf16 weights
    const unsigned long long* __restrict__ pp,  // iidx | pos3<<32 ((tile,k)-sorted)
    const unsigned long long* __restrict__ cdesc,
    const int* __restrict__ csp,                // &cdoffs[tg0*27]
    const int* __restrict__ cep,                // &cdoffs[tg1*27]
    const int* __restrict__ ygbp,               // &ss3[tg0*64]
    unsigned int* __restrict__ Y,               // rows of 32 u32 (bf16 pairs, position layout)
    int ycap)                                   // real rows capacity; dummies at ycap+8+
{
    int c = csp[0] + blockIdx.x * 4 + (threadIdx.x >> 6);
    if (c >= cep[0]) return;
    unsigned long long d = cdesc[c];
    int k     = (int)(d & 31);
    int pbase = (int)((d >> 5) & 0x3FFFFF);
    int pend  = (int)(d >> 27);
    int ygb = ygbp[0];
    int lane  = threadIdx.x & 63;
    int r     = lane & 15;
    int sfour = lane >> 4;
    int par   = lane & 1;

    int ii = pbase + r;
    bool real = ii < pend;
    int pidx = real ? ii : pbase;
    unsigned long long pv = pp[pidx];
    unsigned iidx = (unsigned)(pv & 0xFFFFFFFFull);
    int yr;
    if (real) {
        yr = (int)(pv >> 32) - ygb;
        if (yr > ycap) yr = ycap;               // overflow guard
    } else {
        yr = ycap + 8 + (c & 63);               // spread dummy rows
    }

    const short8_t* xrow = (const short8_t*)(xin + (size_t)iidx * 64);
    short8_t A0 = xrow[sfour];
    short8_t A1 = xrow[4 + sfour];
    const short8_t* wbk = (const short8_t*)(wb + k * 4096);

    f32x4 acc[4] = {{0,0,0,0},{0,0,0,0},{0,0,0,0},{0,0,0,0}};
    #pragma unroll
    for (int n = 0; n < 4; ++n) {
        acc[n] = __builtin_amdgcn_mfma_f32_16x16x32_bf16(A0, wbk[sfour * 64 + n * 16 + r], acc[n], 0, 0, 0);
        acc[n] = __builtin_amdgcn_mfma_f32_16x16x32_bf16(A1, wbk[(4 + sfour) * 64 + n * 16 + r], acc[n], 0, 0, 0);
    }

    // repack D (col=n*16+r, row=sfour*4+j) into bf16 Y rows; lane-pair exchange packs ch pairs
    #pragma unroll
    for (int jj = 0; jj < 4; jj += 2) {
        uint4 w;
        unsigned* wp = (unsigned*)&w;
        #pragma unroll
        for (int n = 0; n < 4; ++n) {
            float mine = par ? acc[n][jj + 1] : acc[n][jj];
            float send = par ? acc[n][jj]     : acc[n][jj + 1];
            float t = __shfl_xor(send, 1, 64);
            float lo = par ? t : mine;
            float hi = par ? mine : t;
            wp[n] = (unsigned)f2bf(lo) | ((unsigned)f2bf(hi) << 16);
        }
        int Rw = sfour * 4 + jj + par;          // pair slot whose row this lane packs
        int yrow = __shfl(yr, Rw, 64);
        ((uint4*)Y)[(size_t)yrow * 8 + (r >> 1)] = w;
    }
}

// ---------- reduce: segmented sum of consecutive Y rows per output + BN(+relu)(+residual) ----------
template<int LAYER>
__global__ __launch_bounds__(256) void reduce_kernel(
    const unsigned int* __restrict__ Y,
    const int* __restrict__ ss3,
    const int* __restrict__ ygbp,
    const float* __restrict__ sbp,              // [0:64) scale, [64:128) shift (position order)
    const float* __restrict__ xres,             // LAYER==1 residual (std layout)
    void* __restrict__ outp,                    // L0: hb (bf16 position layout); L1: f32 std
    int obase, int oend)
{
    int w = blockIdx.x * 4 + (threadIdx.x >> 6);
    int lane = threadIdx.x & 63;
    int q = lane & 7;
    int og = obase + w * 8 + (lane >> 3);
    if (og >= oend) return;
    int ygb = ygbp[0];
    int s0 = ss3[og], s1 = ss3[og + 1];
    int i0 = s0 - ygb, cnt = s1 - s0;

    float sum[8] = {0.f,0.f,0.f,0.f,0.f,0.f,0.f,0.f};
    for (int i = 0; i < cnt; ++i) {
        uint4 v = ((const uint4*)Y)[(size_t)(i0 + i) * 8 + q];
        const unsigned* vp = (const unsigned*)&v;
        #pragma unroll
        for (int t = 0; t < 4; ++t) {
            sum[2 * t]     += bf2f(vp[t] & 0xFFFFu);
            sum[2 * t + 1] += bf2f(vp[t] >> 16);
        }
    }

    const float2* sc2 = (const float2*)sbp;
    const float2* sh2 = (const float2*)(sbp + 64);
    if (LAYER == 0) {
        uint4 o4;
        unsigned* op = (unsigned*)&o4;
        #pragma unroll
        for (int t = 0; t < 4; ++t) {
            int p = q * 4 + t;
            float a = sum[2 * t]     * sc2[p].x + sh2[p].x;
            float b = sum[2 * t + 1] * sc2[p].y + sh2[p].y;
            a = a > 0.f ? a : 0.f;
            b = b > 0.f ? b : 0.f;
            op[t] = (unsigned)f2bf(a) | ((unsigned)f2bf(b) << 16);
        }
        ((uint4*)outp)[(size_t)og * 8 + q] = o4;            // hb row, position layout
    } else {
        float* out = (float*)outp;
        #pragma unroll
        for (int t = 0; t < 4; ++t) {
            int p = q * 4 + t;
            int ch0 = t * 16 + 2 * q;                        // std channel of (p, h=0)
            float2 xr = *(const float2*)(xres + (size_t)og * 64 + ch0);
            float a = sum[2 * t]     * sc2[p].x + sh2[p].x + xr.x;
            float b = sum[2 * t + 1] * sc2[p].y + sh2[p].y + xr.y;
            a = a > 0.f ? a : 0.f;
            b = b > 0.f ? b : 0.f;
            *(float2*)(out + (size_t)og * 64 + ch0) = make_float2(a, b);
        }
    }
}

// ---------------- launch ----------------
extern "C" void kernel_launch(void* const* d_in, const int* in_sizes, int n_in,
                              void* d_out, int out_size, void* d_ws, size_t ws_size,
                              hipStream_t stream)
{
    const float* x  = (const float*)d_in[0];
    const float* w1 = (const float*)d_in[1];
    const float* w2 = (const float*)d_in[2];
    const float* g1 = (const float*)d_in[3];
    const float* b1 = (const float*)d_in[4];
    const float* m1 = (const float*)d_in[5];
    const float* v1 = (const float*)d_in[6];
    const float* g2 = (const float*)d_in[7];
    const float* b2 = (const float*)d_in[8];
    const float* m2 = (const float*)d_in[9];
    const float* v2 = (const float*)d_in[10];
    const int* in_map  = (const int*)d_in[11];
    const int* out_map = (const int*)d_in[12];

    char* ws = (char*)d_ws;
    size_t off = 0;
    auto alloc = [&](size_t bytes) -> void* {
        void* p = ws + off;
        off = (off + bytes + 255) & ~(size_t)255;
        return p;
    };
    // zeroed region: cnt, cursor, cnt3, cur3 (contiguous)
    int* cnt    = (int*)alloc((size_t)NB * 4);
    int* cursor = (int*)alloc((size_t)NB * 4);
    int* cnt3   = (int*)alloc((size_t)N_VOX * 4);
    int* cur3   = (int*)alloc((size_t)N_VOX * 4);
    size_t zlen = (size_t)((char*)cur3 - (char*)cnt) + (size_t)N_VOX * 4;
    int* offs   = (int*)alloc((size_t)(NB + 1) * 4);
    int* ss3    = (int*)alloc((size_t)(N_VOX + 1) * 4);
    int* cdoffs = (int*)alloc((size_t)(NB + 1) * 4);
    int* part   = (int*)alloc(512 * 4);
    float* sbp1 = (float*)alloc(128 * 4);
    float* sbp2 = (float*)alloc(128 * 4);
    unsigned short* wb1 = (unsigned short*)alloc((size_t)WBN * 2);
    unsigned short* wb2 = (unsigned short*)alloc((size_t)WBN * 2);
    unsigned long long* pp = (unsigned long long*)alloc((size_t)KM * 8);
    unsigned long long* cdesc = (unsigned long long*)alloc((size_t)CDCAP * 8);
    unsigned short* xb = (unsigned short*)alloc((size_t)N_VOX * C_CH * 2);
    unsigned short* hb = (unsigned short*)alloc((size_t)N_VOX * C_CH * 2);
    size_t baseB = off;

    // group count by workspace budget: Y holds one group of bf16 rows (+ dummy region)
    const int ngs[5]  = {4, 8, 16, 32, 64};
    const int caps[5] = {690000, 345000, 175000, 90000, 47000};
    int NG = 64, CAP = 47000;
    for (int i = 0; i < 5; ++i) {
        size_t need = baseB + ((size_t)caps[i] + 80) * 128;
        if (ws_size >= need) { NG = ngs[i]; CAP = caps[i]; break; }
    }
    unsigned int* Y = (unsigned int*)alloc(((size_t)CAP + 80) * 128);
    const int TPG = (NT + NG - 1) / NG;

    hipMemsetAsync(cnt, 0, zlen, stream);

    const long TOT = (long)N_VOX * C_CH + 2 * WBN + 128 + KM;
    prep_kernel<<<(int)((TOT + 255) / 256), 256, 0, stream>>>(
        x, w1, w2, g1, b1, m1, v1, g2, b2, m2, v2, out_map,
        xb, wb1, wb2, sbp1, sbp2, cnt, cnt3);

    scanA_kernel<<<NBLK1 + NBLK2, 256, 0, stream>>>(cnt, cnt3, part);
    scanB_kernel<<<3, 128, 0, stream>>>(part);
    scanC_kernel<<<NBLK1 + NBLK2, 256, 0, stream>>>(cnt, cnt3, part, offs, cdoffs, ss3);

    scatter_kernel<<<(KM + 255) / 256, 256, 0, stream>>>(
        in_map, out_map, offs, cursor, ss3, cur3, pp);

    cdescb_kernel<<<(NB + 255) / 256, 256, 0, stream>>>(cnt, offs, cdoffs, cdesc);

    // worst-case chunk count per group -> grid for computeY (early-exit inside)
    const int capC = CAP / 16 + TPG * K_OFF + 8;
    const int cyb = (capC + 3) / 4;

    for (int L = 0; L < 2; ++L) {
        const unsigned short* src = (L == 0) ? xb : hb;
        const unsigned short* wbL = (L == 0) ? wb1 : wb2;
        const float* sbpL = (L == 0) ? sbp1 : sbp2;
        for (int g = 0; g < NG; ++g) {
            int tg0 = g * TPG;
            int tg1 = tg0 + TPG; if (tg1 > NT) tg1 = NT;
            if (tg0 >= tg1) break;
            computeY_kernel<<<cyb, 256, 0, stream>>>(
                src, wbL, pp, cdesc,
                cdoffs + (size_t)tg0 * K_OFF, cdoffs + (size_t)tg1 * K_OFF,
                ss3 + (size_t)tg0 * TILE, Y, CAP);
            int obase = tg0 * TILE, oend = tg1 * TILE;
            int rblocks = (oend - obase + 31) / 32;
            if (L == 0)
                reduce_kernel<0><<<rblocks, 256, 0, stream>>>(
                    Y, ss3, ss3 + (size_t)tg0 * TILE, sbpL, nullptr, hb, obase, oend);
            else
                reduce_kernel<1><<<rblocks, 256, 0, stream>>>(
                    Y, ss3, ss3 + (size_t)tg0 * TILE, sbpL, x, d_out, obase, oend);
        }
    }
}